// Round 10
// baseline (1294.695 us; speedup 1.0000x reference)
//
#include <hip/hip_runtime.h>
#include <hip/hip_bf16.h>

// NSSNN forward on MI355X. x (1,1,31,96,96) fp32. S = 31*96*96 = 285696.
// Round-9 (resubmit; r9 bench was an infra failure): tail conv -> MFMA
// (oc padded to 32, NT=1); head single-launch (z=12, g spans [0,96S)
// pre-wtrans); conv_mfma RS 40->34 (39.98 KB LDS -> 4 blocks/CU,
// 17-dword stride = perfect bank spread).
// Arena (bf16 elems x S): g [0,48) (wt [32,48), head-g [0,96) transient),
// E1/D1 [48,112), E0/D0 [112,144), H [144,160). Total 160*S*2 = 91.4 MB.

#define D_DIM 31
#define H_DIM 96
#define W_DIM 96
#define HW (H_DIM * W_DIM)
#define SVOX (D_DIM * HW)

typedef __hip_bfloat16 bf16;
typedef __attribute__((ext_vector_type(8))) short short8;
typedef __attribute__((ext_vector_type(4))) short short4a;
typedef __attribute__((ext_vector_type(4))) float f32x4;

__device__ __forceinline__ float sigm(float v) { return 1.0f / (1.0f + __expf(-v)); }
__device__ __forceinline__ short f2bs(float v) {
    bf16 h = __float2bfloat16(v);
    return *(short*)&h;
}
__device__ __forceinline__ float bs2f(short s) {
    return __uint_as_float(((unsigned)(unsigned short)s) << 16);
}

template <typename T> __device__ __forceinline__ float ldf(const T* p);
template <> __device__ __forceinline__ float ldf<float>(const float* p) { return *p; }
template <> __device__ __forceinline__ float ldf<bf16>(const bf16* p) {
    return __bfloat162float(*p);
}
template <typename T> __device__ __forceinline__ void stf(T* p, float v);
template <> __device__ __forceinline__ void stf<float>(float* p, float v) { *p = v; }
template <> __device__ __forceinline__ void stf<bf16>(bf16* p, float v) {
    *p = __float2bfloat16(v);
}

#define P8 ((size_t)8 * SVOX)  // elems per i8 channel-block

// ---------------------------------------------------------------------------
// Merged weight transform: wt[region][chunk][kk][oc_c(32)][ci(cip)] bf16.
// Regions (elems): e0 [0,110592) e1 [110592,331776) d0 [331776,552960)
//                  d1 [552960,608256) tail [608256,635904).
// oc_w = (oc_c>>3)*Ch + chunk*8 + (oc_c&7); tail: oc_w = oc_c (<6 valid).
// ---------------------------------------------------------------------------
__global__ __launch_bounds__(256) void wtrans_all_k(const float* __restrict__ w_e0,
                                                    const float* __restrict__ w_e1,
                                                    const float* __restrict__ w_d0,
                                                    const float* __restrict__ w_d1,
                                                    const float* __restrict__ w_tail,
                                                    bf16* __restrict__ wt) {
    int i = blockIdx.x * 256 + threadIdx.x;
    if (i >= 635904) return;
    if (i >= 608256) {  // tail: deconv 16->6, cip=32, oc padded to 32
        int j = i - 608256;
        int ci = j % 32;
        int r = j / 32;
        int oc_c = r & 31;
        int kk = (r >> 5) % 27;
        float v = 0.0f;
        if (ci < 16 && oc_c < 6)
            v = w_tail[(ci * 6 + oc_c) * 27 + (26 - kk)];
        wt[i] = __float2bfloat16(v);
        return;
    }
    const float* w;
    int j, C_in, C_out_w, Ch, deconv, cip;
    if (i < 110592)      { w = w_e0; j = i;          C_in = 16; C_out_w = 128; Ch = 32; deconv = 0; cip = 32; }
    else if (i < 331776) { w = w_e1; j = i - 110592; C_in = 32; C_out_w = 256; Ch = 64; deconv = 0; cip = 32; }
    else if (i < 552960) { w = w_d0; j = i - 331776; C_in = 64; C_out_w = 128; Ch = 32; deconv = 1; cip = 64; }
    else                 { w = w_d1; j = i - 552960; C_in = 32; C_out_w = 64;  Ch = 16; deconv = 1; cip = 32; }
    int ci = j % cip;
    int r = j / cip;
    int oc_c = r & 31; r >>= 5;
    int kk = r % 27;
    int chunk = r / 27;
    int oc_w = (oc_c >> 3) * Ch + chunk * 8 + (oc_c & 7);
    float v = 0.0f;
    if (ci < C_in)
        v = deconv ? w[((size_t)ci * C_out_w + oc_w) * 27 + (26 - kk)]
                   : w[((size_t)oc_w * C_in + ci) * 27 + kk];
    wt[i] = __float2bfloat16(v);
}

// ---------------------------------------------------------------------------
// MFMA implicit-GEMM conv. Grid (24, 31): block = 4 h-rows at depth d.
// NT oc-tiles of 16 (NT=2: 32 compact oc; NT=1: 16, used by tail).
// Staging: slab [6 rows][98 w][32 ci pad34] - one short8 global load +
// one ds_write_b128 per item; 68B lane stride = full 32-bank spread.
// EPI 0: si gates [Wx tanh, ft sigm, rt sigm, X tanh] -> i8 blocks.
// EPI 1: tail plain [6][S], oc<6, act (0,5 tanh; 1-4 sigm).
// ---------------------------------------------------------------------------
template <int CI32, int NT, int EPI>
__global__ __launch_bounds__(256) void conv_mfma_k(const bf16* __restrict__ x,
                                                   const bf16* __restrict__ wt,
                                                   bf16* __restrict__ g, int C_in) {
    constexpr int RS = 34;              // ci slot: 32 + 2 pad (68 B)
    constexpr int CIP = CI32 * 32;      // wt ci stride
    __shared__ short row[6 * 98 * RS];  // 39,984 B -> 4 blocks/CU

    const int t = threadIdx.x;
    const int lane = t & 63, wave = t >> 6;
    const int l15 = lane & 15, g4 = lane >> 4;
    const int h0 = blockIdx.x * 4, d = blockIdx.y;
    const short* xs = (const short*)x;

    f32x4 acc[6][NT];
#pragma unroll
    for (int m = 0; m < 6; ++m)
#pragma unroll
        for (int n = 0; n < NT; ++n) acc[m][n] = (f32x4){0.f, 0.f, 0.f, 0.f};

    for (int kd = 0; kd < 3; ++kd) {
        const int dd = d + kd - 1;
        if ((unsigned)dd >= D_DIM) continue;  // block-uniform
        for (int cb = 0; cb < CI32; ++cb) {
            __syncthreads();
            for (int i = t; i < 98 * 6 * 4; i += 256) {
                int wp = i % 98;
                int j = i / 98;
                int hl = j % 6;
                int cg = j / 6;
                int hh = h0 + hl - 1;
                int gw = wp - 1;
                const int cblk = cb * 4 + cg;
                short8 v = {0, 0, 0, 0, 0, 0, 0, 0};
                if ((unsigned)hh < H_DIM && (unsigned)gw < W_DIM && cblk * 8 < C_in)
                    v = *(const short8*)(xs + (size_t)cblk * P8 +
                                         ((size_t)dd * HW + hh * W_DIM + gw) * 8);
                *(short8*)(row + ((size_t)hl * 98 + wp) * RS + cg * 8) = v;
            }
            __syncthreads();

            const bf16* wa = wt + (size_t)l15 * CIP + cb * 32 + g4 * 8;
#pragma unroll
            for (int kh = 0; kh < 3; ++kh) {
#pragma unroll
                for (int kw = 0; kw < 3; ++kw) {
                    const int kk = (kd * 3 + kh) * 3 + kw;
                    const size_t arow = (size_t)kk * 32 * CIP;
                    short8 a0 = *(const short8*)(wa + arow);
                    short8 a1;
                    if (NT == 2) a1 = *(const short8*)(wa + arow + (size_t)16 * CIP);
                    const int boff = ((wave + kh) * 98 + l15 + kw) * RS + g4 * 8;
#pragma unroll
                    for (int m = 0; m < 6; ++m) {
                        short8 b = *(const short8*)(row + boff + (m * 16) * RS);
                        acc[m][0] = __builtin_amdgcn_mfma_f32_16x16x32_bf16(a0, b, acc[m][0], 0, 0, 0);
                        if (NT == 2)
                            acc[m][1] = __builtin_amdgcn_mfma_f32_16x16x32_bf16(a1, b, acc[m][1], 0, 0, 0);
                    }
                }
            }
        }
    }

    const int hy = h0 + wave;
    short* gs = (short*)g;
#pragma unroll
    for (int m = 0; m < 6; ++m) {
        const int wx = m * 16 + l15;
        const size_t dhw = (size_t)d * HW + hy * W_DIM + wx;
        if (EPI == 0) {
#pragma unroll
            for (int n = 0; n < NT; ++n) {
                const int gate = n * 2 + (g4 >> 1);
                const bool th = (gate == 0 || gate == 3);
                short4a pack;
#pragma unroll
                for (int r = 0; r < 4; ++r) {
                    float a = acc[m][n][r];
                    pack[r] = f2bs(th ? tanhf(a) : sigm(a));
                }
                *(short4a*)(gs + (size_t)gate * P8 + dhw * 8 + (g4 & 1) * 4) = pack;
            }
        } else {
            // tail: oc = g4*4 + r (n=0 only), keep oc<6; plain [oc][S]
#pragma unroll
            for (int r = 0; r < 4; ++r) {
                const int oc = g4 * 4 + r;
                if (oc < 6) {
                    float a = acc[m][0][r];
                    const bool th = (oc == 0 || oc == 5);
                    stf(g + (size_t)oc * SVOX + dhw, th ? tanhf(a) : sigm(a));
                }
            }
        }
    }
}

// ---------------------------------------------------------------------------
// Head conv: direct 3x3x3, C_in=1 (x fp32), 32x32 tile, 2x2 microtile.
// Grid (9,31,12): z -> gate = z>>1, chb = z&1; 8 oc; output i8 block z,
// ACTIVATED. head gates: [Wx(0) tanh, ft..rt2(1-4) sigm, X(5) tanh].
// ---------------------------------------------------------------------------
__global__ __launch_bounds__(256) void head_conv_k(const float* __restrict__ x,
                                                   const float* __restrict__ w,
                                                   bf16* __restrict__ g) {
    __shared__ float tile[3][34][36];
    __shared__ float wsh[8 * 27];

    const int t = threadIdx.x;
    const int lx = t & 15;
    const int ly = t >> 4;
    const int tbx = (blockIdx.x % 3) * 32;
    const int tby = (blockIdx.x / 3) * 32;
    const int d = blockIdx.y;
    const int bz = blockIdx.z;
    const int gate = bz >> 1;
    const int ocw0 = gate * 16 + (bz & 1) * 8;

    if (t < 8 * 27) wsh[t] = w[(ocw0 + t / 27) * 27 + (t % 27)];

    for (int i = t; i < 3 * 34 * 34; i += 256) {
        int dz = i / 1156;
        int rem = i - dz * 1156;
        int r = rem / 34;
        int c = rem - r * 34;
        int gd = d + dz - 1;
        int gy = tby + r - 1;
        int gx = tbx + c - 1;
        float v = 0.0f;
        if ((unsigned)gd < D_DIM && (unsigned)gy < H_DIM && (unsigned)gx < W_DIM)
            v = x[((size_t)gd * H_DIM + gy) * W_DIM + gx];
        tile[dz][r][c] = v;
    }
    __syncthreads();

    float acc[8][4];
#pragma unroll
    for (int o = 0; o < 8; ++o)
#pragma unroll
        for (int p = 0; p < 4; ++p) acc[o][p] = 0.0f;

#pragma unroll
    for (int kd = 0; kd < 3; ++kd)
#pragma unroll
        for (int kh = 0; kh < 3; ++kh) {
            float wv[8][3];
#pragma unroll
            for (int o = 0; o < 8; ++o)
#pragma unroll
                for (int kw = 0; kw < 3; ++kw)
                    wv[o][kw] = wsh[o * 27 + (kd * 3 + kh) * 3 + kw];
            const int r0 = ly * 2 + kh;
            float v0[4], v1[4];
#pragma unroll
            for (int c = 0; c < 4; ++c) {
                v0[c] = tile[kd][r0][lx * 2 + c];
                v1[c] = tile[kd][r0 + 1][lx * 2 + c];
            }
#pragma unroll
            for (int kw = 0; kw < 3; ++kw)
#pragma unroll
                for (int o = 0; o < 8; ++o) {
                    acc[o][0] = fmaf(v0[kw],     wv[o][kw], acc[o][0]);
                    acc[o][1] = fmaf(v0[kw + 1], wv[o][kw], acc[o][1]);
                    acc[o][2] = fmaf(v1[kw],     wv[o][kw], acc[o][2]);
                    acc[o][3] = fmaf(v1[kw + 1], wv[o][kw], acc[o][3]);
                }
        }

    const bool th = (gate == 0 || gate == 5);
    const int hy = tby + ly * 2, wx = tbx + lx * 2;
    short* gs = (short*)g;
#pragma unroll
    for (int p = 0; p < 4; ++p) {
        const int py = hy + (p >> 1), px = wx + (p & 1);
        short8 pack;
#pragma unroll
        for (int o = 0; o < 8; ++o) {
            float a = acc[o][p];
            pack[o] = f2bs(th ? tanhf(a) : sigm(a));
        }
        *(short8*)(gs + (size_t)bz * P8 + ((size_t)d * HW + py * W_DIM + px) * 8) = pack;
    }
}

// ---------------------------------------------------------------------------
// si_sru scan (i8, pre-activated [Wx, f, r, X]); c=idx&7, hw=idx>>3.
// ---------------------------------------------------------------------------
template <int REV>
__global__ __launch_bounds__(256) void si_sru_scan_k(const bf16* __restrict__ g,
                                                     const bf16* __restrict__ resid,
                                                     bf16* __restrict__ out, int outblk) {
    const int idx = blockIdx.x * 256 + threadIdx.x;
    const int c = idx & 7;
    const size_t hw = (size_t)(idx >> 3);
    const size_t ob = (size_t)outblk * P8;

    float C = 0.0f;
#pragma unroll
    for (int i = 0; i < D_DIM; ++i) {
        const int d = REV ? (D_DIM - 1 - i) : i;
        const size_t off = ((size_t)d * HW + hw) * 8 + c;
        float f = ldf(g + P8 + off);
        float r = ldf(g + 2 * P8 + off);
        float xv = ldf(g + 3 * P8 + off);
        float wv = ldf(g + off);
        C = (i == 0) ? (1.0f - f) : (f * C + (1.0f - f) * wv);
        float hv = r * C + (1.0f - r) * xv;
        float o = hv + (resid ? ldf(resid + ob + off) : 0.0f);
        stf(out + ob + off, o);
    }
}

// ---------------------------------------------------------------------------
// do_sru head scan (i8, pre-activated [Wx,f,f2,r,r2,X], gate stride 2*P8),
// grid (288, 2): blockIdx.y = chb. out H block chb.
// ---------------------------------------------------------------------------
__global__ __launch_bounds__(256) void do_sru_scan_k(const bf16* __restrict__ g,
                                                     bf16* __restrict__ out) {
    const int j = blockIdx.x * 256 + threadIdx.x;
    const int c = j & 7;
    const size_t hw = (size_t)(j >> 3);
    const int chb = blockIdx.y;
    const bf16* gb = g + (size_t)chb * P8;  // gate gi at gb + gi*2*P8

    float hbuf[D_DIM];
    float C = 0.0f;
#pragma unroll
    for (int d = 0; d < D_DIM; ++d) {
        const size_t off = ((size_t)d * HW + hw) * 8 + c;
        float f = ldf(gb + 2 * P8 + off);
        float r = ldf(gb + 6 * P8 + off);
        float xv = ldf(gb + 10 * P8 + off);
        float wv = ldf(gb + off);
        C = (d == 0) ? (1.0f - f) : (f * C + (1.0f - f) * wv);
        hbuf[d] = r * C + (1.0f - r) * xv;
    }
#pragma unroll
    for (int i = 0; i < D_DIM; ++i) {
        const int d = D_DIM - 1 - i;
        const size_t off = ((size_t)d * HW + hw) * 8 + c;
        float f = ldf(gb + 4 * P8 + off);
        float r = ldf(gb + 8 * P8 + off);
        float xv = ldf(gb + 10 * P8 + off);
        float wv = ldf(gb + off);
        C = (i == 0) ? (1.0f - f) : (f * C + (1.0f - f) * wv);
        hbuf[d] += r * C + (1.0f - r) * xv;
    }
#pragma unroll
    for (int d = 0; d < D_DIM; ++d)
        stf(out + (size_t)chb * P8 + ((size_t)d * HW + hw) * 8 + c, hbuf[d]);
}

// ---------------------------------------------------------------------------
// Final do_sru: g plain [6][S] pre-activated, resid = x (fp32), out fp32.
// ---------------------------------------------------------------------------
__global__ __launch_bounds__(256) void do_sru_final_k(const bf16* __restrict__ g,
                                                      const float* __restrict__ x,
                                                      float* __restrict__ out) {
    const size_t hw = (size_t)(blockIdx.x * 256 + threadIdx.x);

    float hbuf[D_DIM];
    float C = 0.0f;
#pragma unroll
    for (int d = 0; d < D_DIM; ++d) {
        const size_t off = (size_t)d * HW + hw;
        float f = ldf(g + SVOX + off);
        float r = ldf(g + 3 * (size_t)SVOX + off);
        float xv = ldf(g + 5 * (size_t)SVOX + off);
        float wv = ldf(g + off);
        C = (d == 0) ? (1.0f - f) : (f * C + (1.0f - f) * wv);
        hbuf[d] = r * C + (1.0f - r) * xv;
    }
#pragma unroll
    for (int i = 0; i < D_DIM; ++i) {
        const int d = D_DIM - 1 - i;
        const size_t off = (size_t)d * HW + hw;
        float f = ldf(g + 2 * (size_t)SVOX + off);
        float r = ldf(g + 4 * (size_t)SVOX + off);
        float xv = ldf(g + 5 * (size_t)SVOX + off);
        float wv = ldf(g + off);
        C = (i == 0) ? (1.0f - f) : (f * C + (1.0f - f) * wv);
        hbuf[d] += r * C + (1.0f - r) * xv + x[off];
    }
#pragma unroll
    for (int d = 0; d < D_DIM; ++d) out[(size_t)d * HW + hw] = hbuf[d];
}

// ---------------------------------------------------------------------------
extern "C" void kernel_launch(void* const* d_in, const int* in_sizes, int n_in,
                              void* d_out, int out_size, void* d_ws, size_t ws_size,
                              hipStream_t stream) {
    const float* x      = (const float*)d_in[0];
    const float* w_head = (const float*)d_in[1];  // (96, 1, 27)
    const float* w_e0   = (const float*)d_in[2];  // (128, 16, 27)
    const float* w_e1   = (const float*)d_in[3];  // (256, 32, 27)
    const float* w_d0   = (const float*)d_in[4];  // (64, 128, 27)  deconv
    const float* w_d1   = (const float*)d_in[5];  // (32, 64, 27)   deconv
    const float* w_tail = (const float*)d_in[6];  // (16, 6, 27)    deconv
    float* out = (float*)d_out;

    bf16* g  = (bf16*)d_ws;               // [0,48S); head uses [0,96S) transiently
    bf16* wt = g + (size_t)32 * SVOX;     // [32S,48S): merged weights (635904 el)
    bf16* E1 = g + (size_t)48 * SVOX;     // [48S,112S)
    bf16* E0 = g + (size_t)112 * SVOX;    // [112S,144S)
    bf16* H  = g + (size_t)144 * SVOX;    // [144S,160S)
    bf16* D0 = E0;
    bf16* D1 = E1;                        // uses first 16S of E1 region

    dim3 blk(256);
    const dim3 sg8(8 * 36);            // si scan grid (288 blocks)
    const dim3 mg(H_DIM / 4, D_DIM);   // mfma conv grid (24, 31)

    // 1. head: conv 1->96 (one launch, z=12), do_sru (2 chblks) -> H
    head_conv_k<<<dim3(9, 31, 12), blk, 0, stream>>>(x, w_head, g);
    do_sru_scan_k<<<dim3(288, 2), blk, 0, stream>>>(g, H);
    // merged weight transform (head-g dead now)
    wtrans_all_k<<<dim3((635904 + 255) / 256), blk, 0, stream>>>(w_e0, w_e1, w_d0, w_d1, w_tail, wt);

    // 2. e0: mfma conv 16->128 (4 chunks), si_sru fwd -> E0
    for (int c = 0; c < 4; ++c) {
        conv_mfma_k<1, 2, 0><<<mg, blk, 0, stream>>>(H, wt + (size_t)c * 27648, g, 16);
        si_sru_scan_k<0><<<sg8, blk, 0, stream>>>(g, (const bf16*)nullptr, E0, c);
    }
    // 3. e1: mfma conv 32->256 (8 chunks), si_sru rev -> E1
    for (int c = 0; c < 8; ++c) {
        conv_mfma_k<1, 2, 0><<<mg, blk, 0, stream>>>(E0, wt + 110592 + (size_t)c * 27648, g, 32);
        si_sru_scan_k<1><<<sg8, blk, 0, stream>>>(g, (const bf16*)nullptr, E1, c);
    }
    // 4. d0: mfma deconv 64->128 (4 chunks, CI32=2), si_sru fwd + e0 -> D0
    for (int c = 0; c < 4; ++c) {
        conv_mfma_k<2, 2, 0><<<mg, blk, 0, stream>>>(E1, wt + 331776 + (size_t)c * 55296, g, 64);
        si_sru_scan_k<0><<<sg8, blk, 0, stream>>>(g, E0, D0, c);
    }
    // 5. d1: mfma deconv 32->64 (2 chunks), si_sru rev + h -> D1
    for (int c = 0; c < 2; ++c) {
        conv_mfma_k<1, 2, 0><<<mg, blk, 0, stream>>>(D0, wt + 552960 + (size_t)c * 27648, g, 32);
        si_sru_scan_k<1><<<sg8, blk, 0, stream>>>(g, H, D1, c);
    }
    // 6. tail: mfma deconv 16->6 (oc padded, NT=1) -> g plain [6][S]; final scan
    conv_mfma_k<1, 1, 1><<<mg, blk, 0, stream>>>(D1, wt + 608256, g, 16);
    do_sru_final_k<<<dim3(36), blk, 0, stream>>>(g, x, out);
}

// Round 15
// 1156.322 us; speedup vs baseline: 1.1197x; 1.1197x over previous
//
#include <hip/hip_runtime.h>
#include <hip/hip_bf16.h>

// NSSNN forward on MI355X. x (1,1,31,96,96) fp32. S = 31*96*96 = 285696.
// Round-11 kernel (5th submit; r11-r14 benches were infra failures):
// dual-path. Path A (ws >= ~102MB): NT=4 conv blocks (64 oc), g = 64S,
// 23 launches. Path B (fallback, = r10 structure): NT=2, g = 32S, 41 launches.
// Both: fast tanh/sigm (v_exp + v_rcp), head 16-oc z=6.
// Path A arena (S units): g[0,64) wt[64,67) E1[67,131) E0[131,163) H[163,179)
// Path B arena: g[0,32) wt[32,48) E1[48,112) E0[112,144) H[144,160)

#define D_DIM 31
#define H_DIM 96
#define W_DIM 96
#define HW (H_DIM * W_DIM)
#define SVOX (D_DIM * HW)

typedef __hip_bfloat16 bf16;
typedef __attribute__((ext_vector_type(8))) short short8;
typedef __attribute__((ext_vector_type(4))) short short4a;
typedef __attribute__((ext_vector_type(4))) float f32x4;

__device__ __forceinline__ float rcp_f(float x) { return __builtin_amdgcn_rcpf(x); }
__device__ __forceinline__ float sigm(float v) { return rcp_f(1.0f + __expf(-v)); }
__device__ __forceinline__ float tanh_f(float v) {
    // tanh(x) = 1 - 2/(exp(2x)+1); exp->inf or 0 gives exact +-1.
    return 1.0f - 2.0f * rcp_f(1.0f + __expf(2.0f * v));
}
__device__ __forceinline__ short f2bs(float v) {
    bf16 h = __float2bfloat16(v);
    return *(short*)&h;
}

template <typename T> __device__ __forceinline__ float ldf(const T* p);
template <> __device__ __forceinline__ float ldf<float>(const float* p) { return *p; }
template <> __device__ __forceinline__ float ldf<bf16>(const bf16* p) {
    return __bfloat162float(*p);
}
template <typename T> __device__ __forceinline__ void stf(T* p, float v);
template <> __device__ __forceinline__ void stf<float>(float* p, float v) { *p = v; }
template <> __device__ __forceinline__ void stf<bf16>(bf16* p, float v) {
    *p = __float2bfloat16(v);
}

#define P8 ((size_t)8 * SVOX)  // elems per i8 channel-block

// ---------------------------------------------------------------------------
// Merged weight transform. Regions (elems): e0 [0,110592) e1 [110592,331776)
// d0 [331776,552960) d1 [552960,608256) tail [608256,635904).
// nt4=0: [chunk][kk][oc_c 32][cip]  (r10 layout, NT=2 A tiles)
// nt4=1: [grp][kk][oc64][cip] with chunk = grp*2 + (oc64>>5), oc_c = oc64&31
// tail always [kk][oc 32][ci 32], oc<6 valid (NT=1).
// oc_w = (oc_c>>3)*Ch + chunk*8 + (oc_c&7).
// ---------------------------------------------------------------------------
__global__ __launch_bounds__(256) void wtrans_all_k(const float* __restrict__ w_e0,
                                                    const float* __restrict__ w_e1,
                                                    const float* __restrict__ w_d0,
                                                    const float* __restrict__ w_d1,
                                                    const float* __restrict__ w_tail,
                                                    bf16* __restrict__ wt, int nt4) {
    int i = blockIdx.x * 256 + threadIdx.x;
    if (i >= 635904) return;
    if (i >= 608256) {  // tail
        int j = i - 608256;
        int ci = j % 32;
        int r = j / 32;
        int oc_c = r & 31;
        int kk = (r >> 5) % 27;
        float v = 0.0f;
        if (ci < 16 && oc_c < 6) v = w_tail[(ci * 6 + oc_c) * 27 + (26 - kk)];
        wt[i] = __float2bfloat16(v);
        return;
    }
    const float* w;
    int j, C_in, C_out_w, Ch, deconv, cip;
    if (i < 110592)      { w = w_e0; j = i;          C_in = 16; C_out_w = 128; Ch = 32; deconv = 0; cip = 32; }
    else if (i < 331776) { w = w_e1; j = i - 110592; C_in = 32; C_out_w = 256; Ch = 64; deconv = 0; cip = 32; }
    else if (i < 552960) { w = w_d0; j = i - 331776; C_in = 64; C_out_w = 128; Ch = 32; deconv = 1; cip = 64; }
    else                 { w = w_d1; j = i - 552960; C_in = 32; C_out_w = 64;  Ch = 16; deconv = 1; cip = 32; }
    int ci = j % cip;
    int r = j / cip;
    int oc_c, kk, chunk;
    if (nt4) {
        int oc64 = r & 63; r >>= 6;
        kk = r % 27;
        int grp = r / 27;
        chunk = grp * 2 + (oc64 >> 5);
        oc_c = oc64 & 31;
    } else {
        oc_c = r & 31; r >>= 5;
        kk = r % 27;
        chunk = r / 27;
    }
    int oc_w = (oc_c >> 3) * Ch + chunk * 8 + (oc_c & 7);
    float v = 0.0f;
    if (ci < C_in)
        v = deconv ? w[((size_t)ci * C_out_w + oc_w) * 27 + (26 - kk)]
                   : w[((size_t)oc_w * C_in + ci) * 27 + kk];
    wt[i] = __float2bfloat16(v);
}

// ---------------------------------------------------------------------------
// MFMA implicit-GEMM conv. Grid (24, 31): block = 4 h-rows at depth d,
// NT oc-tiles of 16 (NT=4: 64 oc; NT=2: 32 oc; NT=1: 16, tail).
// Slab [6 rows][98 w][32 ci pad34]: one short8 load + one ds_write_b128/item.
// EPI 0: si gates -> i8 blocks (gate*NCH + cz)*P8; cz = n>>1.
// EPI 1: tail plain [6][S], activated.
// ---------------------------------------------------------------------------
template <int CI32, int NT, int EPI>
__global__ __launch_bounds__(256) void conv_mfma_k(const bf16* __restrict__ x,
                                                   const bf16* __restrict__ wt,
                                                   bf16* __restrict__ g, int C_in,
                                                   int NCH) {
    constexpr int RS = 34;                    // ci slot: 32 + 2 pad (68 B)
    constexpr int CIP = CI32 * 32;            // wt ci stride
    constexpr int AROWS = (NT == 4) ? 64 : 32;
    __shared__ short row[6 * 98 * RS];        // 39,984 B

    const int t = threadIdx.x;
    const int lane = t & 63, wave = t >> 6;
    const int l15 = lane & 15, g4 = lane >> 4;
    const int h0 = blockIdx.x * 4, d = blockIdx.y;
    const short* xs = (const short*)x;

    f32x4 acc[6][NT];
#pragma unroll
    for (int m = 0; m < 6; ++m)
#pragma unroll
        for (int n = 0; n < NT; ++n) acc[m][n] = (f32x4){0.f, 0.f, 0.f, 0.f};

    for (int kd = 0; kd < 3; ++kd) {
        const int dd = d + kd - 1;
        if ((unsigned)dd >= D_DIM) continue;  // block-uniform
        for (int cb = 0; cb < CI32; ++cb) {
            __syncthreads();
            for (int i = t; i < 98 * 6 * 4; i += 256) {
                int wp = i % 98;
                int j = i / 98;
                int hl = j % 6;
                int cg = j / 6;
                int hh = h0 + hl - 1;
                int gw = wp - 1;
                const int cblk = cb * 4 + cg;
                short8 v = {0, 0, 0, 0, 0, 0, 0, 0};
                if ((unsigned)hh < H_DIM && (unsigned)gw < W_DIM && cblk * 8 < C_in)
                    v = *(const short8*)(xs + (size_t)cblk * P8 +
                                         ((size_t)dd * HW + hh * W_DIM + gw) * 8);
                *(short8*)(row + ((size_t)hl * 98 + wp) * RS + cg * 8) = v;
            }
            __syncthreads();

            const bf16* wa = wt + (size_t)l15 * CIP + cb * 32 + g4 * 8;
#pragma unroll
            for (int kh = 0; kh < 3; ++kh) {
#pragma unroll
                for (int kw = 0; kw < 3; ++kw) {
                    const int kk = (kd * 3 + kh) * 3 + kw;
                    short8 a[NT];
#pragma unroll
                    for (int n = 0; n < NT; ++n)
                        a[n] = *(const short8*)(wa + ((size_t)kk * AROWS + n * 16) * CIP);
                    const int boff = ((wave + kh) * 98 + l15 + kw) * RS + g4 * 8;
#pragma unroll
                    for (int m = 0; m < 6; ++m) {
                        short8 b = *(const short8*)(row + boff + (m * 16) * RS);
#pragma unroll
                        for (int n = 0; n < NT; ++n)
                            acc[m][n] = __builtin_amdgcn_mfma_f32_16x16x32_bf16(a[n], b, acc[m][n], 0, 0, 0);
                    }
                }
            }
        }
    }

    const int hy = h0 + wave;
    short* gs = (short*)g;
#pragma unroll
    for (int m = 0; m < 6; ++m) {
        const int wx = m * 16 + l15;
        const size_t dhw = (size_t)d * HW + hy * W_DIM + wx;
        if (EPI == 0) {
#pragma unroll
            for (int n = 0; n < NT; ++n) {
                const int cz = n >> 1;
                const int gate = (n & 1) * 2 + (g4 >> 1);
                const bool th = (gate == 0 || gate == 3);
                short4a pack;
#pragma unroll
                for (int r = 0; r < 4; ++r) {
                    float v = acc[m][n][r];
                    pack[r] = f2bs(th ? tanh_f(v) : sigm(v));
                }
                *(short4a*)(gs + (size_t)(gate * NCH + cz) * P8 + dhw * 8 + (g4 & 1) * 4) = pack;
            }
        } else {
#pragma unroll
            for (int r = 0; r < 4; ++r) {
                const int oc = g4 * 4 + r;
                if (oc < 6) {
                    float v = acc[m][0][r];
                    const bool th = (oc == 0 || oc == 5);
                    stf(g + (size_t)oc * SVOX + dhw, th ? tanh_f(v) : sigm(v));
                }
            }
        }
    }
}

// ---------------------------------------------------------------------------
// Head conv: direct 3x3x3, C_in=1 (x fp32), 32x32 tile, 2x2 microtile,
// 16 oc = one gate per block (uniform activation). Grid (9,31,6).
// Output i8 blocks gate*2 + chb, ACTIVATED.
// ---------------------------------------------------------------------------
__global__ __launch_bounds__(256) void head_conv_k(const float* __restrict__ x,
                                                   const float* __restrict__ w,
                                                   bf16* __restrict__ g) {
    __shared__ float tile[3][34][36];
    __shared__ float wsh[16 * 27];

    const int t = threadIdx.x;
    const int lx = t & 15;
    const int ly = t >> 4;
    const int tbx = (blockIdx.x % 3) * 32;
    const int tby = (blockIdx.x / 3) * 32;
    const int d = blockIdx.y;
    const int gate = blockIdx.z;

    for (int i = t; i < 16 * 27; i += 256)
        wsh[i] = w[(gate * 16 + i / 27) * 27 + (i % 27)];

    for (int i = t; i < 3 * 34 * 34; i += 256) {
        int dz = i / 1156;
        int rem = i - dz * 1156;
        int r = rem / 34;
        int c = rem - r * 34;
        int gd = d + dz - 1;
        int gy = tby + r - 1;
        int gx = tbx + c - 1;
        float v = 0.0f;
        if ((unsigned)gd < D_DIM && (unsigned)gy < H_DIM && (unsigned)gx < W_DIM)
            v = x[((size_t)gd * H_DIM + gy) * W_DIM + gx];
        tile[dz][r][c] = v;
    }
    __syncthreads();

    float acc[16][4];
#pragma unroll
    for (int o = 0; o < 16; ++o)
#pragma unroll
        for (int p = 0; p < 4; ++p) acc[o][p] = 0.0f;

#pragma unroll
    for (int kd = 0; kd < 3; ++kd)
#pragma unroll
        for (int kh = 0; kh < 3; ++kh) {
            const int r0 = ly * 2 + kh;
            float v0[4], v1[4];
#pragma unroll
            for (int c = 0; c < 4; ++c) {
                v0[c] = tile[kd][r0][lx * 2 + c];
                v1[c] = tile[kd][r0 + 1][lx * 2 + c];
            }
#pragma unroll
            for (int half = 0; half < 2; ++half) {
                float wv[8][3];
#pragma unroll
                for (int o = 0; o < 8; ++o)
#pragma unroll
                    for (int kw = 0; kw < 3; ++kw)
                        wv[o][kw] = wsh[(half * 8 + o) * 27 + (kd * 3 + kh) * 3 + kw];
#pragma unroll
                for (int kw = 0; kw < 3; ++kw)
#pragma unroll
                    for (int o = 0; o < 8; ++o) {
                        const int oo = half * 8 + o;
                        acc[oo][0] = fmaf(v0[kw],     wv[o][kw], acc[oo][0]);
                        acc[oo][1] = fmaf(v0[kw + 1], wv[o][kw], acc[oo][1]);
                        acc[oo][2] = fmaf(v1[kw],     wv[o][kw], acc[oo][2]);
                        acc[oo][3] = fmaf(v1[kw + 1], wv[o][kw], acc[oo][3]);
                    }
            }
        }

    const bool th = (gate == 0 || gate == 5);
    const int hy = tby + ly * 2, wx = tbx + lx * 2;
    short* gs = (short*)g;
#pragma unroll
    for (int p = 0; p < 4; ++p) {
        const int py = hy + (p >> 1), px = wx + (p & 1);
        const size_t dhw = (size_t)d * HW + py * W_DIM + px;
#pragma unroll
        for (int chb = 0; chb < 2; ++chb) {
            short8 pack;
#pragma unroll
            for (int u = 0; u < 8; ++u) {
                float v = acc[chb * 8 + u][p];
                pack[u] = f2bs(th ? tanh_f(v) : sigm(v));
            }
            *(short8*)(gs + (size_t)(gate * 2 + chb) * P8 + dhw * 8) = pack;
        }
    }
}

// ---------------------------------------------------------------------------
// si_sru scan (i8, pre-activated [Wx, f, r, X]); c=idx&7, hw=idx>>3.
// Grid (288, NCH): cz = blockIdx.y; gate gi block = gi*NCH + cz;
// out/resid block = outbase + cz. Safe in-place when out==resid.
// ---------------------------------------------------------------------------
template <int REV>
__global__ __launch_bounds__(256) void si_sru_scan_k(const bf16* __restrict__ g,
                                                     const bf16* __restrict__ resid,
                                                     bf16* __restrict__ out,
                                                     int NCH, int outbase) {
    const int idx = blockIdx.x * 256 + threadIdx.x;
    const int c = idx & 7;
    const size_t hw = (size_t)(idx >> 3);
    const int cz = blockIdx.y;
    const bf16* gb = g + (size_t)cz * P8;
    const size_t gs = (size_t)NCH * P8;
    const size_t ob = (size_t)(outbase + cz) * P8;

    float C = 0.0f;
#pragma unroll
    for (int i = 0; i < D_DIM; ++i) {
        const int d = REV ? (D_DIM - 1 - i) : i;
        const size_t off = ((size_t)d * HW + hw) * 8 + c;
        float f = ldf(gb + gs + off);
        float r = ldf(gb + 2 * gs + off);
        float xv = ldf(gb + 3 * gs + off);
        float wv = ldf(gb + off);
        C = (i == 0) ? (1.0f - f) : (f * C + (1.0f - f) * wv);
        float hv = r * C + (1.0f - r) * xv;
        float o = hv + (resid ? ldf(resid + ob + off) : 0.0f);
        stf(out + ob + off, o);
    }
}

// ---------------------------------------------------------------------------
// do_sru head scan (i8 pre-activated [Wx,f,f2,r,r2,X], gate stride 2*P8),
// grid (288, 2): blockIdx.y = chb. out H block chb.
// ---------------------------------------------------------------------------
__global__ __launch_bounds__(256) void do_sru_scan_k(const bf16* __restrict__ g,
                                                     bf16* __restrict__ out) {
    const int j = blockIdx.x * 256 + threadIdx.x;
    const int c = j & 7;
    const size_t hw = (size_t)(j >> 3);
    const int chb = blockIdx.y;
    const bf16* gb = g + (size_t)chb * P8;

    float hbuf[D_DIM];
    float C = 0.0f;
#pragma unroll
    for (int d = 0; d < D_DIM; ++d) {
        const size_t off = ((size_t)d * HW + hw) * 8 + c;
        float f = ldf(gb + 2 * P8 + off);
        float r = ldf(gb + 6 * P8 + off);
        float xv = ldf(gb + 10 * P8 + off);
        float wv = ldf(gb + off);
        C = (d == 0) ? (1.0f - f) : (f * C + (1.0f - f) * wv);
        hbuf[d] = r * C + (1.0f - r) * xv;
    }
#pragma unroll
    for (int i = 0; i < D_DIM; ++i) {
        const int d = D_DIM - 1 - i;
        const size_t off = ((size_t)d * HW + hw) * 8 + c;
        float f = ldf(gb + 4 * P8 + off);
        float r = ldf(gb + 8 * P8 + off);
        float xv = ldf(gb + 10 * P8 + off);
        float wv = ldf(gb + off);
        C = (i == 0) ? (1.0f - f) : (f * C + (1.0f - f) * wv);
        hbuf[d] += r * C + (1.0f - r) * xv;
    }
#pragma unroll
    for (int d = 0; d < D_DIM; ++d)
        stf(out + (size_t)chb * P8 + ((size_t)d * HW + hw) * 8 + c, hbuf[d]);
}

// ---------------------------------------------------------------------------
// Final do_sru: g plain [6][S] pre-activated, resid = x (fp32), out fp32.
// ---------------------------------------------------------------------------
__global__ __launch_bounds__(256) void do_sru_final_k(const bf16* __restrict__ g,
                                                      const float* __restrict__ x,
                                                      float* __restrict__ out) {
    const size_t hw = (size_t)(blockIdx.x * 256 + threadIdx.x);

    float hbuf[D_DIM];
    float C = 0.0f;
#pragma unroll
    for (int d = 0; d < D_DIM; ++d) {
        const size_t off = (size_t)d * HW + hw;
        float f = ldf(g + SVOX + off);
        float r = ldf(g + 3 * (size_t)SVOX + off);
        float xv = ldf(g + 5 * (size_t)SVOX + off);
        float wv = ldf(g + off);
        C = (d == 0) ? (1.0f - f) : (f * C + (1.0f - f) * wv);
        hbuf[d] = r * C + (1.0f - r) * xv;
    }
#pragma unroll
    for (int i = 0; i < D_DIM; ++i) {
        const int d = D_DIM - 1 - i;
        const size_t off = (size_t)d * HW + hw;
        float f = ldf(g + 2 * (size_t)SVOX + off);
        float r = ldf(g + 4 * (size_t)SVOX + off);
        float xv = ldf(g + 5 * (size_t)SVOX + off);
        float wv = ldf(g + off);
        C = (i == 0) ? (1.0f - f) : (f * C + (1.0f - f) * wv);
        hbuf[d] += r * C + (1.0f - r) * xv + x[off];
    }
#pragma unroll
    for (int d = 0; d < D_DIM; ++d) out[(size_t)d * HW + hw] = hbuf[d];
}

// ---------------------------------------------------------------------------
extern "C" void kernel_launch(void* const* d_in, const int* in_sizes, int n_in,
                              void* d_out, int out_size, void* d_ws, size_t ws_size,
                              hipStream_t stream) {
    const float* x      = (const float*)d_in[0];
    const float* w_head = (const float*)d_in[1];
    const float* w_e0   = (const float*)d_in[2];
    const float* w_e1   = (const float*)d_in[3];
    const float* w_d0   = (const float*)d_in[4];
    const float* w_d1   = (const float*)d_in[5];
    const float* w_tail = (const float*)d_in[6];
    float* out = (float*)d_out;
    bf16* ws = (bf16*)d_ws;

    dim3 blk(256);
    const dim3 mg(H_DIM / 4, D_DIM);   // (24, 31)
    const size_t SA = (size_t)SVOX;
    const size_t needA = (size_t)179 * SA * sizeof(bf16);  // ~102.3 MB

    if (ws_size >= needA) {
        // ---- Path A: NT=4, g = 64S, 23 launches ----
        bf16* g  = ws;
        bf16* wt = ws + 64 * SA;
        bf16* E1 = ws + 67 * SA;
        bf16* E0 = ws + 131 * SA;
        bf16* H  = ws + 163 * SA;
        bf16* D0 = E0;
        bf16* D1 = E1;

        head_conv_k<<<dim3(9, 31, 6), blk, 0, stream>>>(x, w_head, g);
        do_sru_scan_k<<<dim3(288, 2), blk, 0, stream>>>(g, H);
        wtrans_all_k<<<dim3(2484), blk, 0, stream>>>(w_e0, w_e1, w_d0, w_d1, w_tail, wt, 1);

        for (int grp = 0; grp < 2; ++grp) {  // e0: 16->128
            conv_mfma_k<1, 4, 0><<<mg, blk, 0, stream>>>(H, wt + (size_t)grp * 55296, g, 16, 2);
            si_sru_scan_k<0><<<dim3(288, 2), blk, 0, stream>>>(g, (const bf16*)nullptr, E0, 2, grp * 2);
        }
        for (int grp = 0; grp < 4; ++grp) {  // e1: 32->256
            conv_mfma_k<1, 4, 0><<<mg, blk, 0, stream>>>(E0, wt + 110592 + (size_t)grp * 55296, g, 32, 2);
            si_sru_scan_k<1><<<dim3(288, 2), blk, 0, stream>>>(g, (const bf16*)nullptr, E1, 2, grp * 2);
        }
        for (int grp = 0; grp < 2; ++grp) {  // d0: deconv 64->128
            conv_mfma_k<2, 4, 0><<<mg, blk, 0, stream>>>(E1, wt + 331776 + (size_t)grp * 110592, g, 64, 2);
            si_sru_scan_k<0><<<dim3(288, 2), blk, 0, stream>>>(g, E0, D0, 2, grp * 2);
        }
        // d1: deconv 32->64 (whole layer)
        conv_mfma_k<1, 4, 0><<<mg, blk, 0, stream>>>(D0, wt + 552960, g, 32, 2);
        si_sru_scan_k<1><<<dim3(288, 2), blk, 0, stream>>>(g, H, D1, 2, 0);
        // tail
        conv_mfma_k<1, 1, 1><<<mg, blk, 0, stream>>>(D1, wt + 608256, g, 16, 1);
        do_sru_final_k<<<dim3(36), blk, 0, stream>>>(g, x, out);
    } else {
        // ---- Path B: NT=2, g = 32S (r10 structure) ----
        bf16* g  = ws;
        bf16* wt = ws + 32 * SA;
        bf16* E1 = ws + 48 * SA;
        bf16* E0 = ws + 112 * SA;
        bf16* H  = ws + 144 * SA;
        bf16* D0 = E0;
        bf16* D1 = E1;

        head_conv_k<<<dim3(9, 31, 6), blk, 0, stream>>>(x, w_head, g);
        do_sru_scan_k<<<dim3(288, 2), blk, 0, stream>>>(g, H);
        wtrans_all_k<<<dim3(2484), blk, 0, stream>>>(w_e0, w_e1, w_d0, w_d1, w_tail, wt, 0);

        for (int c = 0; c < 4; ++c) {
            conv_mfma_k<1, 2, 0><<<mg, blk, 0, stream>>>(H, wt + (size_t)c * 27648, g, 16, 1);
            si_sru_scan_k<0><<<dim3(288, 1), blk, 0, stream>>>(g, (const bf16*)nullptr, E0, 1, c);
        }
        for (int c = 0; c < 8; ++c) {
            conv_mfma_k<1, 2, 0><<<mg, blk, 0, stream>>>(E0, wt + 110592 + (size_t)c * 27648, g, 32, 1);
            si_sru_scan_k<1><<<dim3(288, 1), blk, 0, stream>>>(g, (const bf16*)nullptr, E1, 1, c);
        }
        for (int c = 0; c < 4; ++c) {
            conv_mfma_k<2, 2, 0><<<mg, blk, 0, stream>>>(E1, wt + 331776 + (size_t)c * 55296, g, 64, 1);
            si_sru_scan_k<0><<<dim3(288, 1), blk, 0, stream>>>(g, E0, D0, 1, c);
        }
        for (int c = 0; c < 2; ++c) {
            conv_mfma_k<1, 2, 0><<<mg, blk, 0, stream>>>(D0, wt + 552960 + (size_t)c * 27648, g, 32, 1);
            si_sru_scan_k<1><<<dim3(288, 1), blk, 0, stream>>>(g, H, D1, 1, c);
        }
        conv_mfma_k<1, 1, 1><<<mg, blk, 0, stream>>>(D1, wt + 608256, g, 16, 1);
        do_sru_final_k<<<dim3(36), blk, 0, stream>>>(g, x, out);
    }
}